// Round 8
// baseline (159.585 us; speedup 1.0000x reference)
//
#include <hip/hip_runtime.h>

// ---------------------------------------------------------------------------
// MultiheadAttention: out = (softmax((Xq Wq^T + bq)(Xb Wk^T + bk)^T / 8) (Xb Wv^T + bv)) Wo^T + bo
// B=2, S=2048, D=1024, H=16, hd=64.  All GEMMs + attention in bf16 MFMA, fp32 accum.
// ---------------------------------------------------------------------------

#define BDIM   2
#define SDIM   2048
#define DDIM   1024
#define HEADS  16
#define HD     64
#define MROWS  (BDIM * SDIM)   // 4096

typedef float  f32x4  __attribute__((ext_vector_type(4)));
typedef __bf16 bf16x8 __attribute__((ext_vector_type(8)));
typedef __bf16 bf16x4 __attribute__((ext_vector_type(4)));

// Q scale: 1/sqrt(hd) * log2(e)  (softmax computed in exp2 domain)
#define QSCALE 0.18033688011112042f

__device__ __forceinline__ void stage16(const void* g, void* l) {
    // global -> LDS direct copy, 16B per lane, dest = wave-uniform base + lane*16
    __builtin_amdgcn_global_load_lds((const __attribute__((address_space(1))) void*)g,
                                     (__attribute__((address_space(3))) void*)l,
                                     16, 0, 0);
}

// ---------------------------------------------------------------------------
// fp32 -> bf16 conversion (vectorized: 8 floats -> 16B bf16 per thread)
// ---------------------------------------------------------------------------
__global__ __launch_bounds__(256) void cvt8(const float* __restrict__ in,
                                            __bf16* __restrict__ out, int n8) {
    int i = blockIdx.x * 256 + threadIdx.x;
    if (i >= n8) return;
    const float4* p = (const float4*)in;
    float4 a = p[2 * i];
    float4 c = p[2 * i + 1];
    bf16x8 o;
    o[0] = (__bf16)a.x; o[1] = (__bf16)a.y; o[2] = (__bf16)a.z; o[3] = (__bf16)a.w;
    o[4] = (__bf16)c.x; o[5] = (__bf16)c.y; o[6] = (__bf16)c.z; o[7] = (__bf16)c.w;
    *(bf16x8*)(out + 8 * i) = o;
}

// 4 weight matrices (1M fp32 each) in one launch: blockIdx.x>>9 selects src.
__global__ __launch_bounds__(256) void cvt8w(const float* __restrict__ w0,
                                             const float* __restrict__ w1,
                                             const float* __restrict__ w2,
                                             const float* __restrict__ w3,
                                             __bf16* __restrict__ o0,
                                             __bf16* __restrict__ o1,
                                             __bf16* __restrict__ o2,
                                             __bf16* __restrict__ o3) {
    const int sel = blockIdx.x >> 9;
    const float* in  = (sel == 0) ? w0 : (sel == 1) ? w1 : (sel == 2) ? w2 : w3;
    __bf16*      out = (sel == 0) ? o0 : (sel == 1) ? o1 : (sel == 2) ? o2 : o3;
    int i = (blockIdx.x & 511) * 256 + threadIdx.x;
    const float4* p = (const float4*)in;
    float4 a = p[2 * i];
    float4 c = p[2 * i + 1];
    bf16x8 o;
    o[0] = (__bf16)a.x; o[1] = (__bf16)a.y; o[2] = (__bf16)a.z; o[3] = (__bf16)a.w;
    o[4] = (__bf16)c.x; o[5] = (__bf16)c.y; o[6] = (__bf16)c.z; o[7] = (__bf16)c.w;
    *(bf16x8*)(out + 8 * i) = o;
}

// ---------------------------------------------------------------------------
// B^T GEMM, 2-phase double-buffered (stage tile k+1 under compute of tile k,
// ONE barrier per BK=32 step — T3-minimum; old version serialized staging).
// out[r][n] = sum_k A[r][k] * W[n][k] + bias  — 128x128 tile, 4 waves, LDS 32KB.
// MODE 0: z=blockIdx.z selects {Q,K}; bf16 out in [B,H,S,hd], Q pre-scaled.
// MODE 1: V^T = Wv * Xkv^T: A=Wv (M=1024), W-op=Xkv (N=4096); out [B,H,hd,S]
//         coalesced (this replaces the old z=2 scatter-store epilogue).
// MODE 2: final projection, fp32 out [r][n].
// ---------------------------------------------------------------------------
template <int MODE>
__global__ __launch_bounds__(256) void gemm_bt(
    const __bf16* __restrict__ Aq, const __bf16* __restrict__ Akv,
    const __bf16* __restrict__ W0, const __bf16* __restrict__ W1,
    const float* __restrict__ b0, const float* __restrict__ b1,
    __bf16* __restrict__ Qo, __bf16* __restrict__ Ko, __bf16* __restrict__ Vo,
    float* __restrict__ Fo) {
    __shared__ __align__(16) __bf16 ldsA[2][128 * 32];
    __shared__ __align__(16) __bf16 ldsB[2][128 * 32];

    const int t = threadIdx.x;
    const int l = t & 63;
    const int w = t >> 6;
    const int z = (MODE == 0) ? (int)blockIdx.z : 0;

    const __bf16* A  = (MODE == 0 && z != 0) ? Akv : Aq;
    const __bf16* Wm = (z == 0) ? W0 : W1;
    const float*  bias = (z == 0) ? b0 : b1;

    const int row0 = blockIdx.y * 128;
    const int col0 = blockIdx.x * 128;

    const __bf16* ga = A  + (size_t)(row0 + (t >> 2)) * DDIM + (t & 3) * 8;
    const __bf16* gb = Wm + (size_t)(col0 + (t >> 2)) * DDIM + (t & 3) * 8;
    const int lboff = (t & ~63) * 8;   // wave-uniform element base within buffer

    const int wm = w >> 1, wn = w & 1;
    const int aoff = (wm * 64 + (l & 15)) * 32 + (l >> 4) * 8;
    const int boff = (wn * 64 + (l & 15)) * 32 + (l >> 4) * 8;

    f32x4 acc[4][4] = {};

    // prologue: stage K-step 0 into buffer 0
    stage16(ga,             &ldsA[0][lboff]);
    stage16(ga + 64 * DDIM, &ldsA[0][lboff + 2048]);
    stage16(gb,             &ldsB[0][lboff]);
    stage16(gb + 64 * DDIM, &ldsB[0][lboff + 2048]);

    for (int step = 0; step < DDIM / 32; ++step) {
        const int bb = step & 1;
        __syncthreads();   // buf[bb] staged (vmcnt drain) & prev reads of buf[bb] done

        if (step + 1 < DDIM / 32) {
            const int kb = (step + 1) * 32;
            stage16(ga + kb,             &ldsA[bb ^ 1][lboff]);
            stage16(ga + kb + 64 * DDIM, &ldsA[bb ^ 1][lboff + 2048]);
            stage16(gb + kb,             &ldsB[bb ^ 1][lboff]);
            stage16(gb + kb + 64 * DDIM, &ldsB[bb ^ 1][lboff + 2048]);
        }

        bf16x8 af[4], bf[4];
#pragma unroll
        for (int m = 0; m < 4; ++m) af[m] = *(const bf16x8*)(&ldsA[bb][aoff + m * 16 * 32]);
#pragma unroll
        for (int n = 0; n < 4; ++n) bf[n] = *(const bf16x8*)(&ldsB[bb][boff + n * 16 * 32]);
#pragma unroll
        for (int m = 0; m < 4; ++m)
#pragma unroll
            for (int n = 0; n < 4; ++n)
                acc[m][n] = __builtin_amdgcn_mfma_f32_16x16x32_bf16(af[m], bf[n], acc[m][n], 0, 0, 0);
    }

    // ---- epilogue: C/D layout col = lane&15, row = (lane>>4)*4 + j ----
#pragma unroll
    for (int m = 0; m < 4; ++m) {
        const int rbase = row0 + wm * 64 + m * 16 + (l >> 4) * 4;
#pragma unroll
        for (int n = 0; n < 4; ++n) {
            const int col = col0 + wn * 64 + n * 16 + (l & 15);
            if constexpr (MODE == 0) {
                const float bv = bias[col];
                const int hh = col >> 6, d = col & 63;
#pragma unroll
                for (int j = 0; j < 4; ++j) {
                    const int r = rbase + j;
                    const int b = r >> 11, s = r & 2047;
                    const float v = acc[m][n][j] + bv;
                    if (z == 0) {
                        Qo[(((b * HEADS + hh) * SDIM + s) << 6) + d] = (__bf16)(v * QSCALE);
                    } else {
                        Ko[(((b * HEADS + hh) * SDIM + s) << 6) + d] = (__bf16)v;
                    }
                }
            } else if constexpr (MODE == 1) {
                // rows = feature f (h*64+d), cols = b*2048+s -> [B,H,hd,S]
                const int b = col >> 11, s = col & 2047;
#pragma unroll
                for (int j = 0; j < 4; ++j) {
                    const int f = rbase + j;      // 0..1023
                    Vo[(size_t)(b * DDIM + f) * SDIM + s] = (__bf16)(acc[m][n][j] + bias[f]);
                }
            } else {
                const float bv = bias[col];
#pragma unroll
                for (int j = 0; j < 4; ++j) {
                    Fo[(size_t)(rbase + j) * DDIM + col] = acc[m][n][j] + bv;
                }
            }
        }
    }
}

// ---------------------------------------------------------------------------
// Flash attention v7 (unchanged): 512 blocks x 512 threads = 8 waves x 16
// q-rows, KVBLK=128 (two 64-row sub-tiles per barrier round), XCD
// head-clustering, swapped QK^T + sigma-permuted K staging, XOR-swizzled LDS,
// no-max exp2 softmax, row-sum on the MFMA pipe.  LDS 64 KB.
// ---------------------------------------------------------------------------
__global__ __launch_bounds__(512) void attn_fwd(const __bf16* __restrict__ Qb,
                                                const __bf16* __restrict__ Kb,
                                                const __bf16* __restrict__ Vtb,
                                                __bf16* __restrict__ Cb) {
    __shared__ __align__(16) __bf16 ldsK[2][2][64 * 64];
    __shared__ __align__(16) __bf16 ldsV[2][2][64 * 64];

    const int t = threadIdx.x;        // 0..511
    const int l = t & 63;
    const int w = t >> 6;             // 0..7
    const int i15 = l & 15;
    const int q4 = l >> 4;

    // --- XCD head-clustering decode (bijective on 512 blocks) ---
    const int bid  = blockIdx.x;
    const int xcd  = bid & 7;
    const int wloc = bid >> 3;               // 0..63 within XCD
    const int bh   = xcd * 4 + (wloc >> 4);  // 4 (b,h) pairs per XCD
    const int qb   = wloc & 15;              // q-block within head (consecutive)
    const int b    = bh >> 4;
    const int h    = bh & 15;
    const size_t base = (size_t)bh * SDIM * HD;
    const int q0 = qb * 128;

    // Q fragments (B-operand of swapped QK^T): col=q=i15, k-dim=d
    const __bf16* qp = Qb + base + (size_t)(q0 + w * 16 + i15) * HD + q4 * 8;
    const bf16x8 qf0 = *(const bf16x8*)(qp);
    const bf16x8 qf1 = *(const bf16x8*)(qp + 32);

    // --- staging source addresses (rule 21: linear LDS dest, permuted source)
    const int r0 = t >> 3;                    // LDS row this thread fills
    const int sl = (t & 7) ^ (r0 & 7);        // source slot = phys slot ^ row&7
    const int sig0 = ((r0 >> 5) << 5) | (((r0 >> 2) & 3) << 3)
                   | (((r0 >> 4) & 1) << 2) | (r0 & 3);      // sigma-permuted K row
    const __bf16* gk = Kb  + base + (size_t)sig0 * HD + sl * 8;
    const __bf16* gv = Vtb + base + (size_t)r0 * SDIM + sl * 8;
    const int wb = (t & ~63) * 8;             // wave-uniform LDS element base

    // --- swizzled read offsets (elements), same table for K and V reads ---
    const int xr = i15 & 7;
    int off[4][2];
#pragma unroll
    for (int n = 0; n < 4; ++n)
#pragma unroll
        for (int hh = 0; hh < 2; ++hh)
            off[n][hh] = (n * 16 + i15) * 64 + (((hh * 4 + q4) ^ xr) << 3);

    // ones fragment for the MFMA row-sum
    bf16x8 ones;
#pragma unroll
    for (int j = 0; j < 8; ++j) ones[j] = (__bf16)1.0f;

    f32x4 c[4] = {};
    f32x4 lsum = {};

    // prologue: stage round 0 (two 64-row sub-tiles of K and V) into buffer 0
    stage16(gk,           &ldsK[0][0][wb]);
    stage16(gk + 64 * HD, &ldsK[0][1][wb]);
    stage16(gv,           &ldsV[0][0][wb]);
    stage16(gv + 64,      &ldsV[0][1][wb]);

    for (int r = 0; r < SDIM / 128; ++r) {
        const int bb = r & 1;
        __syncthreads();   // buf[bb] staged & prev compute on buf[bb^1] done

        if (r + 1 < SDIM / 128) {
            const int s0 = (r + 1) * 128;
            stage16(gk + (size_t)s0 * HD,        &ldsK[bb ^ 1][0][wb]);
            stage16(gk + (size_t)(s0 + 64) * HD, &ldsK[bb ^ 1][1][wb]);
            stage16(gv + s0,                     &ldsV[bb ^ 1][0][wb]);
            stage16(gv + s0 + 64,                &ldsV[bb ^ 1][1][wb]);
        }

        const __bf16* lk0 = &ldsK[bb][0][0];
        const __bf16* lk1 = &ldsK[bb][1][0];
        const __bf16* lv0 = &ldsV[bb][0][0];
        const __bf16* lv1 = &ldsV[bb][1][0];

        // ---- QK^T (swapped), both halves: sA/sB hold S^T[k-block n][q] ----
        f32x4 sA[4] = {}, sB[4] = {};
        __builtin_amdgcn_s_setprio(1);
#pragma unroll
        for (int n = 0; n < 4; ++n) {
            bf16x8 k0 = *(const bf16x8*)(lk0 + off[n][0]);
            bf16x8 k1 = *(const bf16x8*)(lk0 + off[n][1]);
            sA[n] = __builtin_amdgcn_mfma_f32_16x16x32_bf16(k0, qf0, sA[n], 0, 0, 0);
            sA[n] = __builtin_amdgcn_mfma_f32_16x16x32_bf16(k1, qf1, sA[n], 0, 0, 0);
        }
#pragma unroll
        for (int n = 0; n < 4; ++n) {
            bf16x8 k0 = *(const bf16x8*)(lk1 + off[n][0]);
            bf16x8 k1 = *(const bf16x8*)(lk1 + off[n][1]);
            sB[n] = __builtin_amdgcn_mfma_f32_16x16x32_bf16(k0, qf0, sB[n], 0, 0, 0);
            sB[n] = __builtin_amdgcn_mfma_f32_16x16x32_bf16(k1, qf1, sB[n], 0, 0, 0);
        }
        __builtin_amdgcn_s_setprio(0);

        // ---- softmax numerator: raw exp2 (no max, no cross-lane), both halves ----
#pragma unroll
        for (int n = 0; n < 4; ++n)
#pragma unroll
            for (int j = 0; j < 4; ++j) {
                sA[n][j] = exp2f(sA[n][j]);
                sB[n][j] = exp2f(sB[n][j]);
            }

        // ---- pack P^T fragments (lane-local; k-order matches V columns) ----
        bf16x8 paA0, paB0, paA1, paB1;
#pragma unroll
        for (int j = 0; j < 4; ++j) {
            paA0[j]     = (__bf16)sA[0][j];
            paA0[j + 4] = (__bf16)sA[1][j];
            paB0[j]     = (__bf16)sA[2][j];
            paB0[j + 4] = (__bf16)sA[3][j];
            paA1[j]     = (__bf16)sB[0][j];
            paA1[j + 4] = (__bf16)sB[1][j];
            paB1[j]     = (__bf16)sB[2][j];
            paB1[j + 4] = (__bf16)sB[3][j];
        }

        // ---- PV + MFMA row-sum, both halves ----
        __builtin_amdgcn_s_setprio(1);
        lsum = __builtin_amdgcn_mfma_f32_16x16x32_bf16(ones, paA0, lsum, 0, 0, 0);
        lsum = __builtin_amdgcn_mfma_f32_16x16x32_bf16(ones, paB0, lsum, 0, 0, 0);
        lsum = __builtin_amdgcn_mfma_f32_16x16x32_bf16(ones, paA1, lsum, 0, 0, 0);
        lsum = __builtin_amdgcn_mfma_f32_16x16x32_bf16(ones, paB1, lsum, 0, 0, 0);
#pragma unroll
        for (int n2 = 0; n2 < 4; ++n2) {
            bf16x8 v0 = *(const bf16x8*)(lv0 + off[n2][0]);
            bf16x8 v1 = *(const bf16x8*)(lv0 + off[n2][1]);
            c[n2] = __builtin_amdgcn_mfma_f32_16x16x32_bf16(v0, paA0, c[n2], 0, 0, 0);
            c[n2] = __builtin_amdgcn_mfma_f32_16x16x32_bf16(v1, paB0, c[n2], 0, 0, 0);
            bf16x8 u0 = *(const bf16x8*)(lv1 + off[n2][0]);
            bf16x8 u1 = *(const bf16x8*)(lv1 + off[n2][1]);
            c[n2] = __builtin_amdgcn_mfma_f32_16x16x32_bf16(u0, paA1, c[n2], 0, 0, 0);
            c[n2] = __builtin_amdgcn_mfma_f32_16x16x32_bf16(u1, paB1, c[n2], 0, 0, 0);
        }
        __builtin_amdgcn_s_setprio(0);
    }

    // ---- write ctx (merged heads, bf16): [B, S, D], 8B vector stores ----
    const float inv = 1.0f / lsum[0];
    const int q = q0 + w * 16 + i15;
#pragma unroll
    for (int n2 = 0; n2 < 4; ++n2) {
        bf16x4 o;
#pragma unroll
        for (int j = 0; j < 4; ++j) o[j] = (__bf16)(c[n2][j] * inv);
        *(bf16x4*)(Cb + (size_t)(b * SDIM + q) * DDIM + h * HD + n2 * 16 + q4 * 4) = o;
    }
}

// ---------------------------------------------------------------------------
extern "C" void kernel_launch(void* const* d_in, const int* in_sizes, int n_in,
                              void* d_out, int out_size, void* d_ws, size_t ws_size,
                              hipStream_t stream) {
    const float* query = (const float*)d_in[0];
    const float* bank  = (const float*)d_in[1];
    const float* Wq = (const float*)d_in[2];
    const float* bq = (const float*)d_in[3];
    const float* Wk = (const float*)d_in[4];
    const float* bk = (const float*)d_in[5];
    const float* Wv = (const float*)d_in[6];
    const float* bv = (const float*)d_in[7];
    const float* Wo = (const float*)d_in[8];
    const float* bo = (const float*)d_in[9];
    float* out = (float*)d_out;

    char* ws = (char*)d_ws;
    __bf16* xq  = (__bf16*)(ws);                    // 8 MB  [4096,1024] (reused as ctx)
    __bf16* xkv = (__bf16*)(ws + (8u  << 20));      // 8 MB
    __bf16* wq  = (__bf16*)(ws + (16u << 20));      // 2 MB
    __bf16* wk  = (__bf16*)(ws + (18u << 20));      // 2 MB
    __bf16* wv  = (__bf16*)(ws + (20u << 20));      // 2 MB
    __bf16* wo  = (__bf16*)(ws + (22u << 20));      // 2 MB
    __bf16* qbuf = (__bf16*)(ws + (24u << 20));     // 8 MB [B,H,S,hd] (scaled)
    __bf16* kbuf = (__bf16*)(ws + (32u << 20));     // 8 MB [B,H,S,hd]
    __bf16* vtbuf = (__bf16*)(ws + (40u << 20));    // 8 MB [B,H,hd,S]
    __bf16* ctx = xq;                               // alias: xq dead after QKV gemm

    // fp32 -> bf16
    cvt8<<<2048, 256, 0, stream>>>(query, xq, 524288);
    cvt8<<<2048, 256, 0, stream>>>(bank, xkv, 524288);
    cvt8w<<<2048, 256, 0, stream>>>(Wq, Wk, Wv, Wo, wq, wk, wv, wo);

    // Q,K projections (z=0 -> Q, z=1 -> K)
    gemm_bt<0><<<dim3(8, 32, 2), 256, 0, stream>>>(
        xq, xkv, wq, wk, bq, bk, qbuf, kbuf, nullptr, nullptr);

    // V^T = Wv * Xkv^T  (coalesced [B,H,hd,S] output)
    gemm_bt<1><<<dim3(32, 8, 1), 256, 0, stream>>>(
        wv, nullptr, xkv, nullptr, bv, nullptr, nullptr, nullptr, vtbuf, nullptr);

    // flash attention (1D grid, XCD head-clustering decode inside)
    attn_fwd<<<512, 512, 0, stream>>>(qbuf, kbuf, vtbuf, ctx);

    // output projection (fp32 out)
    gemm_bt<2><<<dim3(8, 32, 1), 256, 0, stream>>>(
        ctx, nullptr, wo, nullptr, bo, nullptr, nullptr, nullptr, nullptr, out);
}

// Round 9
// 128.546 us; speedup vs baseline: 1.2415x; 1.2415x over previous
//
#include <hip/hip_runtime.h>

// ---------------------------------------------------------------------------
// MultiheadAttention: out = (softmax((Xq Wq^T + bq)(Xb Wk^T + bk)^T / 8) (Xb Wv^T + bv)) Wo^T + bo
// B=2, S=2048, D=1024, H=16, hd=64.  All GEMMs + attention in bf16 MFMA, fp32 accum.
// ---------------------------------------------------------------------------

#define BDIM   2
#define SDIM   2048
#define DDIM   1024
#define HEADS  16
#define HD     64
#define MROWS  (BDIM * SDIM)   // 4096

typedef float  f32x4  __attribute__((ext_vector_type(4)));
typedef __bf16 bf16x8 __attribute__((ext_vector_type(8)));
typedef __bf16 bf16x4 __attribute__((ext_vector_type(4)));

// Q scale: 1/sqrt(hd) * log2(e)  (softmax computed in exp2 domain)
#define QSCALE 0.18033688011112042f

__device__ __forceinline__ void stage16(const void* g, void* l) {
    // global -> LDS direct copy, 16B per lane, dest = wave-uniform base + lane*16
    __builtin_amdgcn_global_load_lds((const __attribute__((address_space(1))) void*)g,
                                     (__attribute__((address_space(3))) void*)l,
                                     16, 0, 0);
}

// ---------------------------------------------------------------------------
// ALL fp32 -> bf16 conversions in ONE launch (was 3 launches).
// chunks: query 524288, bank 524288, then 4 weights x 131072 (8 floats each).
// ---------------------------------------------------------------------------
__global__ __launch_bounds__(256) void cvt_all(
    const float* __restrict__ q, const float* __restrict__ bank,
    const float* __restrict__ Wq, const float* __restrict__ Wk,
    const float* __restrict__ Wv, const float* __restrict__ Wo,
    __bf16* __restrict__ xq, __bf16* __restrict__ xkv,
    __bf16* __restrict__ wq, __bf16* __restrict__ wk,
    __bf16* __restrict__ wv, __bf16* __restrict__ wo) {
    const int i = blockIdx.x * 256 + threadIdx.x;   // 0..1572863
    const float* in;
    __bf16* out;
    int off;
    if (i < 524288)       { in = q;    out = xq;  off = i; }
    else if (i < 1048576) { in = bank; out = xkv; off = i - 524288; }
    else {
        const int j = i - 1048576;
        const int sel = j >> 17;
        off = j & 131071;
        in  = (sel == 0) ? Wq : (sel == 1) ? Wk : (sel == 2) ? Wv : Wo;
        out = (sel == 0) ? wq : (sel == 1) ? wk : (sel == 2) ? wv : wo;
    }
    const float4* p = (const float4*)in;
    float4 a = p[2 * off];
    float4 c = p[2 * off + 1];
    bf16x8 o;
    o[0] = (__bf16)a.x; o[1] = (__bf16)a.y; o[2] = (__bf16)a.z; o[3] = (__bf16)a.w;
    o[4] = (__bf16)c.x; o[5] = (__bf16)c.y; o[6] = (__bf16)c.z; o[7] = (__bf16)c.w;
    *(bf16x8*)(out + 8 * off) = o;
}

// ---------------------------------------------------------------------------
// B^T GEMM (round-7 proven structure: 2-barrier loop, single 16 KB LDS buf,
// cross-block overlap at >=2 blocks/CU provides the pipelining — m114).
// out[r][n] = sum_k A[r][k] * W[n][k] + bias.
// MODE 0: 128x128 tile, z=blockIdx.z selects {Q,K,V}; bf16 head-split outputs
//         (V transposed [B,H,hd,S] via scatter epilogue).
// MODE 2: 128x64 tile (grid 2x blocks -> 2/CU for the tail launch), fp32 out.
// ---------------------------------------------------------------------------
template <int MODE>
__global__ __launch_bounds__(256) void gemm_bt(
    const __bf16* __restrict__ Aq, const __bf16* __restrict__ Akv,
    const __bf16* __restrict__ W0, const __bf16* __restrict__ W1,
    const __bf16* __restrict__ W2,
    const float* __restrict__ b0, const float* __restrict__ b1,
    const float* __restrict__ b2,
    __bf16* __restrict__ Qo, __bf16* __restrict__ Ko, __bf16* __restrict__ Vo,
    float* __restrict__ Fo) {
    constexpr int NF = (MODE == 2) ? 2 : 4;        // n-fragments per wave
    constexpr int NCOL = NF * 32;                  // block col-tile (64 or 128)
    __shared__ __align__(16) __bf16 ldsA[128 * 32];
    __shared__ __align__(16) __bf16 ldsB[(NCOL)*32];

    const int t = threadIdx.x;
    const int l = t & 63;
    const int w = t >> 6;
    const int z = (MODE == 0) ? (int)blockIdx.z : 0;

    const __bf16* A  = (MODE == 0 && z != 0) ? Akv : Aq;
    const __bf16* Wm = (z == 0) ? W0 : (z == 1 ? W1 : W2);
    const float*  bias = (z == 0) ? b0 : (z == 1 ? b1 : b2);

    const int row0 = blockIdx.y * 128;
    const int col0 = blockIdx.x * NCOL;

    const __bf16* ga = A  + (size_t)(row0 + (t >> 2)) * DDIM + (t & 3) * 8;
    const __bf16* gb = Wm + (size_t)(col0 + (t >> 2)) * DDIM + (t & 3) * 8;
    __bf16* la = ldsA + (t & ~63) * 8;  // wave-uniform base
    __bf16* lb = ldsB + (t & ~63) * 8;

    const int wm = w >> 1, wn = w & 1;
    const int aoff = (wm * 64 + (l & 15)) * 32 + (l >> 4) * 8;
    const int boff = (wn * (NF * 16) + (l & 15)) * 32 + (l >> 4) * 8;

    f32x4 acc[4][NF] = {};

    for (int kb = 0; kb < DDIM; kb += 32) {
        __syncthreads();
        stage16(ga + kb,             la);
        stage16(ga + kb + 64 * DDIM, la + 2048);
        stage16(gb + kb,             lb);
        if constexpr (MODE == 0)
            stage16(gb + kb + 64 * DDIM, lb + 2048);
        __syncthreads();

        bf16x8 af[4], bf[NF];
#pragma unroll
        for (int m = 0; m < 4; ++m) af[m] = *(const bf16x8*)(ldsA + aoff + m * 16 * 32);
#pragma unroll
        for (int n = 0; n < NF; ++n) bf[n] = *(const bf16x8*)(ldsB + boff + n * 16 * 32);
#pragma unroll
        for (int m = 0; m < 4; ++m)
#pragma unroll
            for (int n = 0; n < NF; ++n)
                acc[m][n] = __builtin_amdgcn_mfma_f32_16x16x32_bf16(af[m], bf[n], acc[m][n], 0, 0, 0);
    }

    // ---- epilogue: C/D layout col = lane&15, row = (lane>>4)*4 + j ----
#pragma unroll
    for (int m = 0; m < 4; ++m) {
        const int rbase = row0 + wm * 64 + m * 16 + (l >> 4) * 4;
#pragma unroll
        for (int n = 0; n < NF; ++n) {
            const int col = col0 + wn * (NF * 16) + n * 16 + (l & 15);
            const float bv = bias[col];
            if constexpr (MODE == 0) {
                const int hh = col >> 6, d = col & 63;
#pragma unroll
                for (int j = 0; j < 4; ++j) {
                    const int r = rbase + j;
                    const int b = r >> 11, s = r & 2047;
                    const float v = acc[m][n][j] + bv;
                    if (z == 0) {
                        Qo[(((b * HEADS + hh) * SDIM + s) << 6) + d] = (__bf16)(v * QSCALE);
                    } else if (z == 1) {
                        Ko[(((b * HEADS + hh) * SDIM + s) << 6) + d] = (__bf16)v;
                    } else {  // V stored transposed: [B,H,hd,S]
                        Vo[(((b * HEADS + hh) * HD + d) << 11) + s] = (__bf16)v;
                    }
                }
            } else {
#pragma unroll
                for (int j = 0; j < 4; ++j) {
                    Fo[(size_t)(rbase + j) * DDIM + col] = acc[m][n][j] + bv;
                }
            }
        }
    }
}

// ---------------------------------------------------------------------------
// Flash attention v7b: 512 blocks x 512 threads = 8 waves x 16 q-rows,
// KVBLK=128 (two 64-row sub-tiles per barrier round), XCD head-clustering,
// swapped QK^T + sigma-permuted K staging, XOR-swizzled LDS, no-max exp2
// softmax, row-sum on the MFMA pipe.  LDS 64 KB.
// v7b: KV loop unrolled x2 so bb const-folds (LDS bases become immediates).
// ---------------------------------------------------------------------------
__global__ __launch_bounds__(512) void attn_fwd(const __bf16* __restrict__ Qb,
                                                const __bf16* __restrict__ Kb,
                                                const __bf16* __restrict__ Vtb,
                                                __bf16* __restrict__ Cb) {
    __shared__ __align__(16) __bf16 ldsK[2][2][64 * 64];
    __shared__ __align__(16) __bf16 ldsV[2][2][64 * 64];

    const int t = threadIdx.x;        // 0..511
    const int l = t & 63;
    const int w = t >> 6;             // 0..7
    const int i15 = l & 15;
    const int q4 = l >> 4;

    // --- XCD head-clustering decode (bijective on 512 blocks) ---
    const int bid  = blockIdx.x;
    const int xcd  = bid & 7;
    const int wloc = bid >> 3;               // 0..63 within XCD
    const int bh   = xcd * 4 + (wloc >> 4);  // 4 (b,h) pairs per XCD
    const int qb   = wloc & 15;              // q-block within head (consecutive)
    const int b    = bh >> 4;
    const int h    = bh & 15;
    const size_t base = (size_t)bh * SDIM * HD;
    const int q0 = qb * 128;

    // Q fragments (B-operand of swapped QK^T): col=q=i15, k-dim=d
    const __bf16* qp = Qb + base + (size_t)(q0 + w * 16 + i15) * HD + q4 * 8;
    const bf16x8 qf0 = *(const bf16x8*)(qp);
    const bf16x8 qf1 = *(const bf16x8*)(qp + 32);

    // --- staging source addresses (rule 21: linear LDS dest, permuted source)
    const int r0 = t >> 3;                    // LDS row this thread fills
    const int sl = (t & 7) ^ (r0 & 7);        // source slot = phys slot ^ row&7
    const int sig0 = ((r0 >> 5) << 5) | (((r0 >> 2) & 3) << 3)
                   | (((r0 >> 4) & 1) << 2) | (r0 & 3);      // sigma-permuted K row
    const __bf16* gk = Kb  + base + (size_t)sig0 * HD + sl * 8;
    const __bf16* gv = Vtb + base + (size_t)r0 * SDIM + sl * 8;
    const int wb = (t & ~63) * 8;             // wave-uniform LDS element base

    // --- swizzled read offsets (elements), same table for K and V reads ---
    const int xr = i15 & 7;
    int off[4][2];
#pragma unroll
    for (int n = 0; n < 4; ++n)
#pragma unroll
        for (int hh = 0; hh < 2; ++hh)
            off[n][hh] = (n * 16 + i15) * 64 + (((hh * 4 + q4) ^ xr) << 3);

    // ones fragment for the MFMA row-sum
    bf16x8 ones;
#pragma unroll
    for (int j = 0; j < 8; ++j) ones[j] = (__bf16)1.0f;

    f32x4 c[4] = {};
    f32x4 lsum = {};

    // prologue: stage round 0 (two 64-row sub-tiles of K and V) into buffer 0
    stage16(gk,           &ldsK[0][0][wb]);
    stage16(gk + 64 * HD, &ldsK[0][1][wb]);
    stage16(gv,           &ldsV[0][0][wb]);
    stage16(gv + 64,      &ldsV[0][1][wb]);

#pragma unroll 2
    for (int r = 0; r < SDIM / 128; ++r) {
        const int bb = r & 1;
        __syncthreads();   // buf[bb] staged & prev compute on buf[bb^1] done

        if (r + 1 < SDIM / 128) {
            const int s0 = (r + 1) * 128;
            stage16(gk + (size_t)s0 * HD,        &ldsK[bb ^ 1][0][wb]);
            stage16(gk + (size_t)(s0 + 64) * HD, &ldsK[bb ^ 1][1][wb]);
            stage16(gv + s0,                     &ldsV[bb ^ 1][0][wb]);
            stage16(gv + s0 + 64,                &ldsV[bb ^ 1][1][wb]);
        }

        const __bf16* lk0 = &ldsK[bb][0][0];
        const __bf16* lk1 = &ldsK[bb][1][0];
        const __bf16* lv0 = &ldsV[bb][0][0];
        const __bf16* lv1 = &ldsV[bb][1][0];

        // ---- QK^T (swapped), both halves: sA/sB hold S^T[k-block n][q] ----
        f32x4 sA[4] = {}, sB[4] = {};
        __builtin_amdgcn_s_setprio(1);
#pragma unroll
        for (int n = 0; n < 4; ++n) {
            bf16x8 k0 = *(const bf16x8*)(lk0 + off[n][0]);
            bf16x8 k1 = *(const bf16x8*)(lk0 + off[n][1]);
            sA[n] = __builtin_amdgcn_mfma_f32_16x16x32_bf16(k0, qf0, sA[n], 0, 0, 0);
            sA[n] = __builtin_amdgcn_mfma_f32_16x16x32_bf16(k1, qf1, sA[n], 0, 0, 0);
        }
#pragma unroll
        for (int n = 0; n < 4; ++n) {
            bf16x8 k0 = *(const bf16x8*)(lk1 + off[n][0]);
            bf16x8 k1 = *(const bf16x8*)(lk1 + off[n][1]);
            sB[n] = __builtin_amdgcn_mfma_f32_16x16x32_bf16(k0, qf0, sB[n], 0, 0, 0);
            sB[n] = __builtin_amdgcn_mfma_f32_16x16x32_bf16(k1, qf1, sB[n], 0, 0, 0);
        }
        __builtin_amdgcn_s_setprio(0);

        // ---- softmax numerator: raw exp2 (no max, no cross-lane), both halves ----
#pragma unroll
        for (int n = 0; n < 4; ++n)
#pragma unroll
            for (int j = 0; j < 4; ++j) {
                sA[n][j] = exp2f(sA[n][j]);
                sB[n][j] = exp2f(sB[n][j]);
            }

        // ---- pack P^T fragments (lane-local; k-order matches V columns) ----
        bf16x8 paA0, paB0, paA1, paB1;
#pragma unroll
        for (int j = 0; j < 4; ++j) {
            paA0[j]     = (__bf16)sA[0][j];
            paA0[j + 4] = (__bf16)sA[1][j];
            paB0[j]     = (__bf16)sA[2][j];
            paB0[j + 4] = (__bf16)sA[3][j];
            paA1[j]     = (__bf16)sB[0][j];
            paA1[j + 4] = (__bf16)sB[1][j];
            paB1[j]     = (__bf16)sB[2][j];
            paB1[j + 4] = (__bf16)sB[3][j];
        }

        // ---- PV + MFMA row-sum, both halves ----
        __builtin_amdgcn_s_setprio(1);
        lsum = __builtin_amdgcn_mfma_f32_16x16x32_bf16(ones, paA0, lsum, 0, 0, 0);
        lsum = __builtin_amdgcn_mfma_f32_16x16x32_bf16(ones, paB0, lsum, 0, 0, 0);
        lsum = __builtin_amdgcn_mfma_f32_16x16x32_bf16(ones, paA1, lsum, 0, 0, 0);
        lsum = __builtin_amdgcn_mfma_f32_16x16x32_bf16(ones, paB1, lsum, 0, 0, 0);
#pragma unroll
        for (int n2 = 0; n2 < 4; ++n2) {
            bf16x8 v0 = *(const bf16x8*)(lv0 + off[n2][0]);
            bf16x8 v1 = *(const bf16x8*)(lv0 + off[n2][1]);
            c[n2] = __builtin_amdgcn_mfma_f32_16x16x32_bf16(v0, paA0, c[n2], 0, 0, 0);
            c[n2] = __builtin_amdgcn_mfma_f32_16x16x32_bf16(v1, paB0, c[n2], 0, 0, 0);
            bf16x8 u0 = *(const bf16x8*)(lv1 + off[n2][0]);
            bf16x8 u1 = *(const bf16x8*)(lv1 + off[n2][1]);
            c[n2] = __builtin_amdgcn_mfma_f32_16x16x32_bf16(u0, paA1, c[n2], 0, 0, 0);
            c[n2] = __builtin_amdgcn_mfma_f32_16x16x32_bf16(u1, paB1, c[n2], 0, 0, 0);
        }
        __builtin_amdgcn_s_setprio(0);
    }

    // ---- write ctx (merged heads, bf16): [B, S, D], 8B vector stores ----
    const float inv = 1.0f / lsum[0];
    const int q = q0 + w * 16 + i15;
#pragma unroll
    for (int n2 = 0; n2 < 4; ++n2) {
        bf16x4 o;
#pragma unroll
        for (int j = 0; j < 4; ++j) o[j] = (__bf16)(c[n2][j] * inv);
        *(bf16x4*)(Cb + (size_t)(b * SDIM + q) * DDIM + h * HD + n2 * 16 + q4 * 4) = o;
    }
}

// ---------------------------------------------------------------------------
extern "C" void kernel_launch(void* const* d_in, const int* in_sizes, int n_in,
                              void* d_out, int out_size, void* d_ws, size_t ws_size,
                              hipStream_t stream) {
    const float* query = (const float*)d_in[0];
    const float* bank  = (const float*)d_in[1];
    const float* Wq = (const float*)d_in[2];
    const float* bq = (const float*)d_in[3];
    const float* Wk = (const float*)d_in[4];
    const float* bk = (const float*)d_in[5];
    const float* Wv = (const float*)d_in[6];
    const float* bv = (const float*)d_in[7];
    const float* Wo = (const float*)d_in[8];
    const float* bo = (const float*)d_in[9];
    float* out = (float*)d_out;

    char* ws = (char*)d_ws;
    __bf16* xq  = (__bf16*)(ws);                    // 8 MB  [4096,1024] (reused as ctx)
    __bf16* xkv = (__bf16*)(ws + (8u  << 20));      // 8 MB
    __bf16* wq  = (__bf16*)(ws + (16u << 20));      // 2 MB
    __bf16* wk  = (__bf16*)(ws + (18u << 20));      // 2 MB
    __bf16* wv  = (__bf16*)(ws + (20u << 20));      // 2 MB
    __bf16* wo  = (__bf16*)(ws + (22u << 20));      // 2 MB
    __bf16* qbuf = (__bf16*)(ws + (24u << 20));     // 8 MB [B,H,S,hd] (scaled)
    __bf16* kbuf = (__bf16*)(ws + (32u << 20));     // 8 MB [B,H,S,hd]
    __bf16* vtbuf = (__bf16*)(ws + (40u << 20));    // 8 MB [B,H,hd,S]
    __bf16* ctx = xq;                               // alias: xq dead after QKV gemm

    // fp32 -> bf16 (single launch for all 6 tensors)
    cvt_all<<<6144, 256, 0, stream>>>(query, bank, Wq, Wk, Wv, Wo,
                                      xq, xkv, wq, wk, wv, wo);

    // fused QKV projections (z=0 Q, z=1 K, z=2 V^T) — 768 blocks, 3/CU
    gemm_bt<0><<<dim3(8, 32, 3), 256, 0, stream>>>(
        xq, xkv, wq, wk, wv, bq, bk, bv, qbuf, kbuf, vtbuf, nullptr);

    // flash attention (1D grid, XCD head-clustering decode inside)
    attn_fwd<<<512, 512, 0, stream>>>(qbuf, kbuf, vtbuf, ctx);

    // output projection (fp32 out) — 128x64 tile, 512 blocks, 2/CU
    gemm_bt<2><<<dim3(16, 32, 1), 256, 0, stream>>>(
        ctx, nullptr, wo, nullptr, nullptr, bo, nullptr, nullptr,
        nullptr, nullptr, nullptr, out);
}